// Round 1
// baseline (1509.117 us; speedup 1.0000x reference)
//
#include <hip/hip_runtime.h>
#include <stdint.h>

// TransposedAttention (XCA) on MI355X.
// Pipeline per batch:
//   K1  qkv = Wqkv(576x192) @ x(192x65536)        [bf16 MFMA GEMM, out bf16]
//   K2b dwconv3x3 on q,k channels -> LDS, Gram qk^T (MFMA) + ||q||^2,||k||^2 atomics
//   K1b qkv for v channels (reuses buffer A)
//   K2a dwconv3x3 on v channels -> v (bf16)
//   K3  attn = softmax(norm'd Gram * temp); Weff = Wproj x attn  (192x192 bf16)
//   K5  y = Weff(192x192) @ v(192x65536)          [bf16 MFMA GEMM, out fp32]
// q,k post-conv are never written to HBM; attention+proj collapsed into Weff.
//
// ws layout (bytes), peak 75,818,496:
//   0         bufA   [384][65536] bf16  (qk stage; rows 0..191 reused for v stage)
//   50331648  vbuf   [192][65536] bf16
//   75497472  gram   6*1024 + qq 192 + kk 192  fp32 (6528 floats)
//   75523584  weff   [192][192] bf16
//   75597312  wqbf   [576][192] bf16

#define NPIX 65536
#define WROW 256

typedef __attribute__((ext_vector_type(4))) float f32x4;
typedef __attribute__((ext_vector_type(8))) short bf16x8;
typedef __attribute__((ext_vector_type(4))) unsigned short u16x4;

__device__ __forceinline__ float bf2f(unsigned short h){
  unsigned int u = ((unsigned int)h) << 16; float f; __builtin_memcpy(&f,&u,4); return f;
}
__device__ __forceinline__ unsigned short f2bf(float f){
  unsigned int u; __builtin_memcpy(&u,&f,4);
  u = (u + 0x7FFFu + ((u>>16)&1u)) >> 16;   // RNE
  return (unsigned short)u;
}

__global__ void k_zero(float* __restrict__ p, int n){
  int i = blockIdx.x*256 + threadIdx.x;
  if(i < n) p[i] = 0.f;
}

__global__ void k_cvt_w(const float* __restrict__ w, unsigned short* __restrict__ o, int n){
  int i = blockIdx.x*256 + threadIdx.x;
  if(i < n) o[i] = f2bf(w[i]);
}

// ---------------- K1: pointwise GEMM  out[row][n] = sum_c wq[row][c]*x[c][n] ----------------
// block: 256 thr = 4 waves, tile 192(M) x 64(N); wave = 48x64 (3x4 frags of 16x16x32 bf16)
__global__ __launch_bounds__(256) void k_qkv_gemm(
    const float* __restrict__ x,            // [192][NPIX] fp32
    const unsigned short* __restrict__ wq,  // [rows][192] bf16 (pre-offset)
    unsigned short* __restrict__ out)       // [rows][NPIX] bf16
{
  __shared__ __align__(16) unsigned short Bs[64*40];  // [n][c], stride 40 (2-way-bank-safe)
  const int tid  = threadIdx.x;
  const int lane = tid & 63;
  const int wv   = tid >> 6;
  const int quad = lane >> 4;
  const int l16  = lane & 15;
  const int nb   = blockIdx.x * 64;
  const int ob   = blockIdx.y * 192 + wv * 48;

  f32x4 acc[3][4];
#pragma unroll
  for(int i=0;i<3;i++)
#pragma unroll
    for(int j=0;j<4;j++) acc[i][j] = (f32x4){0.f,0.f,0.f,0.f};

  const int cl = tid >> 3;        // 0..31 : c within k-slice
  const int nn = (tid & 7) * 8;   // 0..56 : n base

  for(int kc=0;kc<6;kc++){
    const int c0 = kc*32;
    __syncthreads();
    const float* xp = x + (size_t)(c0+cl)*NPIX + nb + nn;
    f32x4 v0 = *(const f32x4*)xp;
    f32x4 v1 = *(const f32x4*)(xp+4);
#pragma unroll
    for(int j=0;j<4;j++) Bs[(nn+j)*40 + cl]   = f2bf(v0[j]);
#pragma unroll
    for(int j=0;j<4;j++) Bs[(nn+4+j)*40 + cl] = f2bf(v1[j]);
    __syncthreads();

    bf16x8 a[3];
#pragma unroll
    for(int i=0;i<3;i++)
      a[i] = *(const bf16x8*)(wq + (size_t)(ob + i*16 + l16)*192 + c0 + quad*8);
#pragma unroll
    for(int j=0;j<4;j++){
      bf16x8 b = *(const bf16x8*)&Bs[(j*16 + l16)*40 + quad*8];
#pragma unroll
      for(int i=0;i<3;i++)
        acc[i][j] = __builtin_amdgcn_mfma_f32_16x16x32_bf16(a[i], b, acc[i][j], 0,0,0);
    }
  }
#pragma unroll
  for(int i=0;i<3;i++)
#pragma unroll
    for(int j=0;j<4;j++){
      const int o = ob + i*16 + quad*4;           // C/D: row=(lane>>4)*4+reg, col=lane&15
      const int n = nb + j*16 + l16;
      unsigned short* op = out + (size_t)o*NPIX + n;
#pragma unroll
      for(int r=0;r<4;r++) op[(size_t)r*NPIX] = f2bf(acc[i][j][r]);
    }
}

// ---------------- K2a: depthwise 3x3 on v channels ----------------
__global__ __launch_bounds__(256) void k_dwconv_v(
    const unsigned short* __restrict__ src, // [192][NPIX] = channels 384..575
    const float* __restrict__ wdw,          // [576][9]
    unsigned short* __restrict__ v)         // [192][NPIX]
{
  const int c  = blockIdx.y;
  const int n0 = blockIdx.x*1024 + threadIdx.x*4;
  const int y  = n0 >> 8;
  const int x0 = n0 & 255;
  const float* wp = wdw + (size_t)(384 + c)*9;
  const float w00=wp[0],w01=wp[1],w02=wp[2],w10=wp[3],w11=wp[4],w12=wp[5],w20=wp[6],w21=wp[7],w22=wp[8];
  const unsigned short* in = src + (size_t)c*NPIX;
  const unsigned short* r0 = in + (y-1)*WROW;
  const unsigned short* r1 = in + y*WROW;
  const unsigned short* r2 = in + (y+1)*WROW;
  const bool ht = (y>0), hb = (y<255);
  float t0,m0,b0,t1,m1,b1;
  if(x0>0){ t0 = ht? bf2f(r0[x0-1]):0.f; m0 = bf2f(r1[x0-1]); b0 = hb? bf2f(r2[x0-1]):0.f; }
  else    { t0=m0=b0=0.f; }
  t1 = ht? bf2f(r0[x0]):0.f; m1 = bf2f(r1[x0]); b1 = hb? bf2f(r2[x0]):0.f;
  u16x4 ov;
#pragma unroll
  for(int j=0;j<4;j++){
    const int xx = x0+j;
    float t2,m2,b2;
    if(xx<255){ t2 = ht? bf2f(r0[xx+1]):0.f; m2 = bf2f(r1[xx+1]); b2 = hb? bf2f(r2[xx+1]):0.f; }
    else      { t2=m2=b2=0.f; }
    const float s = t0*w00+t1*w01+t2*w02 + m0*w10+m1*w11+m2*w12 + b0*w20+b1*w21+b2*w22;
    ov[j] = f2bf(s);
    t0=t1;t1=t2;m0=m1;m1=m2;b0=b1;b1=b2;
  }
  *(u16x4*)(v + (size_t)c*NPIX + n0) = ov;
}

// 32-px sliding-window dw conv for one (channel,row,x-chunk); returns sum of squares
__device__ __forceinline__ float conv_row32(
    const unsigned short* __restrict__ in, const float* __restrict__ wp,
    int y, int x0, unsigned short* __restrict__ dst)
{
  const float w00=wp[0],w01=wp[1],w02=wp[2],w10=wp[3],w11=wp[4],w12=wp[5],w20=wp[6],w21=wp[7],w22=wp[8];
  const unsigned short* r0 = in + (y-1)*WROW;
  const unsigned short* r1 = in + y*WROW;
  const unsigned short* r2 = in + (y+1)*WROW;
  const bool ht = (y>0), hb = (y<255);
  float t0,m0,b0,t1,m1,b1;
  if(x0>0){ t0 = ht? bf2f(r0[x0-1]):0.f; m0 = bf2f(r1[x0-1]); b0 = hb? bf2f(r2[x0-1]):0.f; }
  else    { t0=m0=b0=0.f; }
  t1 = ht? bf2f(r0[x0]):0.f; m1 = bf2f(r1[x0]); b1 = hb? bf2f(r2[x0]):0.f;
  float ss = 0.f;
#pragma unroll 8
  for(int j=0;j<32;j++){
    const int xx = x0+j;
    float t2,m2,b2;
    if(xx<255){ t2 = ht? bf2f(r0[xx+1]):0.f; m2 = bf2f(r1[xx+1]); b2 = hb? bf2f(r2[xx+1]):0.f; }
    else      { t2=m2=b2=0.f; }
    const float s = t0*w00+t1*w01+t2*w02 + m0*w10+m1*w11+m2*w12 + b0*w20+b1*w21+b2*w22;
    ss += s*s;
    dst[j] = f2bf(s);
    t0=t1;t1=t2;m0=m1;m1=m2;b0=b1;b1=b2;
  }
  return ss;
}

// ---------------- K2b: dw conv on q,k + Gram(q k^T) + norms ----------------
// block = (row y, head h): 32 q-ch + 32 k-ch over one 256-px row -> LDS; MFMA 32x32 Gram
__global__ __launch_bounds__(256) void k_dwconv_qk_gram(
    const unsigned short* __restrict__ qk,  // [384][NPIX]
    const float* __restrict__ wdw,
    float* __restrict__ gram,               // [6][32][32]
    float* __restrict__ qqg,                // [192]
    float* __restrict__ kkg)                // [192]
{
  __shared__ __align__(16) unsigned short qbuf[32*264];  // stride 264: bank-safe, 16B-aligned
  __shared__ __align__(16) unsigned short kbuf[32*264];
  __shared__ float qqs[32], kks[32];
  const int tid = threadIdx.x;
  const int h   = blockIdx.y;
  const int y   = blockIdx.x;        // 0..255
  const int ch  = tid >> 3;          // 0..31
  const int x0  = (tid & 7) * 32;
  if(tid < 32){ qqs[tid]=0.f; kks[tid]=0.f; }
  __syncthreads();

  const int gq = h*32 + ch;
  const int gk = 192 + h*32 + ch;
  const float sq = conv_row32(qk + (size_t)gq*NPIX, wdw + (size_t)gq*9, y, x0, &qbuf[ch*264 + x0]);
  const float sk = conv_row32(qk + (size_t)gk*NPIX, wdw + (size_t)gk*9, y, x0, &kbuf[ch*264 + x0]);
  atomicAdd(&qqs[ch], sq);
  atomicAdd(&kks[ch], sk);
  __syncthreads();
  if(tid < 32)      atomicAdd(&qqg[h*32 + tid], qqs[tid]);
  else if(tid < 64) atomicAdd(&kkg[h*32 + tid - 32], kks[tid-32]);

  // Gram: G[d][e] += sum_n q[d][n]*k[e][n]  (A and B both row-major-in-n: gemm_bt layout)
  const int lane = tid & 63;
  const int wv   = tid >> 6;
  const int quad = lane >> 4;
  const int l16  = lane & 15;
  const int d0   = (wv & 1) * 16;
  const int e0   = (wv >> 1) * 16;
  f32x4 acc = (f32x4){0.f,0.f,0.f,0.f};
#pragma unroll
  for(int n0=0;n0<256;n0+=32){
    bf16x8 a = *(const bf16x8*)&qbuf[(d0+l16)*264 + n0 + quad*8];
    bf16x8 b = *(const bf16x8*)&kbuf[(e0+l16)*264 + n0 + quad*8];
    acc = __builtin_amdgcn_mfma_f32_16x16x32_bf16(a, b, acc, 0,0,0);
  }
  float* gp = gram + (size_t)h*1024;
#pragma unroll
  for(int r=0;r<4;r++)
    atomicAdd(&gp[(d0 + quad*4 + r)*32 + e0 + l16], acc[r]);
}

// ---------------- K3: attn softmax + Weff = Wproj x blockdiag(attn) ----------------
__global__ __launch_bounds__(256) void k_attn_weff(
    const float* __restrict__ gram, const float* __restrict__ qqg,
    const float* __restrict__ kkg,  const float* __restrict__ temp,
    const float* __restrict__ wproj, unsigned short* __restrict__ weff)
{
  __shared__ float attn[192*32];
  __shared__ float rkk[192];
  const int tid = threadIdx.x;
  if(tid < 192) rkk[tid] = 1.0f / fmaxf(sqrtf(kkg[tid]), 1e-12f);
  __syncthreads();
  if(tid < 192){
    const int h = tid >> 5, d = tid & 31;
    const float rq = 1.0f / fmaxf(sqrtf(qqg[tid]), 1e-12f);
    const float tp = fminf(temp[h], 5.0f);
    float l[32];
    float mx = -1e30f;
#pragma unroll
    for(int e=0;e<32;e++){
      l[e] = gram[(size_t)h*1024 + d*32 + e] * rq * rkk[h*32+e] * tp;
      mx = fmaxf(mx, l[e]);
    }
    float s = 0.f;
#pragma unroll
    for(int e=0;e<32;e++){ l[e] = __expf(l[e]-mx); s += l[e]; }
    const float inv = 1.0f/s;
#pragma unroll
    for(int e=0;e<32;e++) attn[tid*32+e] = l[e]*inv;
  }
  __syncthreads();
  // Weff[o][h*32+e] = sum_d wproj[o][h*32+d] * attn[h][d][e]; this block: 24 o-rows
  for(int idx = tid; idx < 24*192; idx += 256){
    const int o  = blockIdx.x*24 + idx/192;
    const int cc = idx - (idx/192)*192;
    const int h2 = cc >> 5, e = cc & 31;
    const float* wpp = wproj + (size_t)o*192 + h2*32;
    float s = 0.f;
#pragma unroll
    for(int d=0; d<32; d++) s += wpp[d]*attn[(h2*32+d)*32 + e];
    weff[(size_t)o*192 + cc] = f2bf(s);
  }
}

// ---------------- K5: y = Weff(192x192) @ v(192xN), fp32 out ----------------
__global__ __launch_bounds__(256) void k_proj_gemm(
    const unsigned short* __restrict__ v,    // [192][NPIX] bf16
    const unsigned short* __restrict__ weff, // [192][192] bf16
    float* __restrict__ out)                 // [192][NPIX] fp32
{
  __shared__ __align__(16) unsigned short Bs[64*40];
  const int tid  = threadIdx.x;
  const int lane = tid & 63;
  const int wv   = tid >> 6;
  const int quad = lane >> 4;
  const int l16  = lane & 15;
  const int nb   = blockIdx.x * 64;
  const int ob   = wv * 48;
  f32x4 acc[3][4];
#pragma unroll
  for(int i=0;i<3;i++)
#pragma unroll
    for(int j=0;j<4;j++) acc[i][j] = (f32x4){0.f,0.f,0.f,0.f};
  const int cl = tid >> 3;
  const int nn = (tid & 7)*8;

  for(int kc=0;kc<6;kc++){
    const int c0 = kc*32;
    __syncthreads();
    bf16x8 vv = *(const bf16x8*)(v + (size_t)(c0+cl)*NPIX + nb + nn);
#pragma unroll
    for(int j=0;j<8;j++) Bs[(nn+j)*40 + cl] = (unsigned short)vv[j];
    __syncthreads();
    bf16x8 a[3];
#pragma unroll
    for(int i=0;i<3;i++)
      a[i] = *(const bf16x8*)(weff + (size_t)(ob+i*16+l16)*192 + c0 + quad*8);
#pragma unroll
    for(int j=0;j<4;j++){
      bf16x8 b = *(const bf16x8*)&Bs[(j*16+l16)*40 + quad*8];
#pragma unroll
      for(int i=0;i<3;i++)
        acc[i][j] = __builtin_amdgcn_mfma_f32_16x16x32_bf16(a[i], b, acc[i][j], 0,0,0);
    }
  }
#pragma unroll
  for(int i=0;i<3;i++)
#pragma unroll
    for(int j=0;j<4;j++){
      const int o = ob + i*16 + quad*4;
      const int n = nb + j*16 + l16;
      float* op = out + (size_t)o*NPIX + n;
#pragma unroll
      for(int r=0;r<4;r++) op[(size_t)r*NPIX] = acc[i][j][r];
    }
}

extern "C" void kernel_launch(void* const* d_in, const int* in_sizes, int n_in,
                              void* d_out, int out_size, void* d_ws, size_t ws_size,
                              hipStream_t stream)
{
  (void)in_sizes; (void)n_in; (void)out_size; (void)ws_size;
  const float* x     = (const float*)d_in[0];
  const float* wqkv  = (const float*)d_in[1];
  const float* wdw   = (const float*)d_in[2];
  const float* wproj = (const float*)d_in[3];
  const float* temp  = (const float*)d_in[4];
  float* out = (float*)d_out;

  char* ws = (char*)d_ws;
  unsigned short* bufA = (unsigned short*)(ws);              // 50,331,648 B
  unsigned short* vbuf = (unsigned short*)(ws + 50331648);   // 25,165,824 B
  float*          gram = (float*)(ws + 75497472);            // 6528 floats
  unsigned short* weff = (unsigned short*)(ws + 75523584);   // 73,728 B
  unsigned short* wqbf = (unsigned short*)(ws + 75597312);   // 221,184 B
  float* qqg = gram + 6*1024;
  float* kkg = qqg + 192;

  k_cvt_w<<<dim3(432), dim3(256), 0, stream>>>(wqkv, wqbf, 576*192);

  for(int b=0;b<2;b++){
    const float* xb = x + (size_t)b*192*NPIX;
    float* outb = out + (size_t)b*192*NPIX;
    k_zero<<<dim3(26), dim3(256), 0, stream>>>(gram, 6528);
    // q,k channels (0..383) -> bufA
    k_qkv_gemm<<<dim3(1024,2), dim3(256), 0, stream>>>(xb, wqbf, bufA);
    k_dwconv_qk_gram<<<dim3(256,6), dim3(256), 0, stream>>>(bufA, wdw, gram, qqg, kkg);
    // v channels (384..575) -> bufA rows 0..191 (reuse)
    k_qkv_gemm<<<dim3(1024,1), dim3(256), 0, stream>>>(xb, wqbf + (size_t)384*192, bufA);
    k_dwconv_v<<<dim3(64,192), dim3(256), 0, stream>>>(bufA, wdw, vbuf);
    k_attn_weff<<<dim3(8), dim3(256), 0, stream>>>(gram, qqg, kkg, temp, wproj, weff);
    k_proj_gemm<<<dim3(1024), dim3(256), 0, stream>>>(vbuf, weff, outb);
  }
}

// Round 2
// 1288.513 us; speedup vs baseline: 1.1712x; 1.1712x over previous
//
#include <hip/hip_runtime.h>
#include <stdint.h>

// TransposedAttention (XCA) on MI355X.
// Pipeline per batch:
//   K1  qkv(qk rows) = Wqkv @ x            [bf16 MFMA GEMM, out bf16] -> bufA
//   per head-group hg in {0,1} (3 heads each):
//     K2 dwconv3x3 on 96 q + 96 k channels -> vbuf (bf16), + ||.||^2 atomics
//     K3 Gram q.k^T per head               [MFMA, LDS-staged, atomicAdd]
//   K1b qkv(v rows) -> bufA ; K2a dwconv v -> vbuf
//   K4  attn = softmax(norm'd Gram * temp); Weff = Wproj x blockdiag(attn)
//   K5  y = Weff(192x192) @ v(192x65536)   [bf16 MFMA GEMM, out fp32]
// Attention+projection collapsed into Weff; conv'd q,k round-trip through
// vbuf in two head-groups to stay inside the 75.8 MB workspace footprint.
//
// ws layout (bytes), peak 75,818,496:
//   0         bufA   [384][65536] bf16
//   50331648  vbuf   [192][65536] bf16  (conv'd qk per head-group; later conv'd v)
//   75497472  gram   6*1024 + qq 192 + kk 192  fp32 (6528 floats)
//   75523584  weff   [192][192] bf16
//   75597312  wqbf   [576][192] bf16

#define NPIX 65536
#define WROW 256

typedef __attribute__((ext_vector_type(4))) float f32x4;
typedef __attribute__((ext_vector_type(8))) short bf16x8;
typedef __attribute__((ext_vector_type(4))) unsigned short u16x4;

__device__ __forceinline__ float bf2f(unsigned short h){
  unsigned int u = ((unsigned int)h) << 16; float f; __builtin_memcpy(&f,&u,4); return f;
}
__device__ __forceinline__ unsigned short f2bf(float f){
  unsigned int u; __builtin_memcpy(&u,&f,4);
  u = (u + 0x7FFFu + ((u>>16)&1u)) >> 16;   // RNE
  return (unsigned short)u;
}

__global__ void k_zero(float* __restrict__ p, int n){
  int i = blockIdx.x*256 + threadIdx.x;
  if(i < n) p[i] = 0.f;
}

__global__ void k_cvt_w(const float* __restrict__ w, unsigned short* __restrict__ o, int n){
  int i = blockIdx.x*256 + threadIdx.x;
  if(i < n) o[i] = f2bf(w[i]);
}

// ---------------- K1: pointwise GEMM  out[row][n] = sum_c wq[row][c]*x[c][n] ----------------
__global__ __launch_bounds__(256) void k_qkv_gemm(
    const float* __restrict__ x,            // [192][NPIX] fp32
    const unsigned short* __restrict__ wq,  // [rows][192] bf16 (pre-offset)
    unsigned short* __restrict__ out)       // [rows][NPIX] bf16
{
  __shared__ __align__(16) unsigned short Bs[64*40];  // [n][c], stride 40
  const int tid  = threadIdx.x;
  const int lane = tid & 63;
  const int wv   = tid >> 6;
  const int quad = lane >> 4;
  const int l16  = lane & 15;
  const int nb   = blockIdx.x * 64;
  const int ob   = blockIdx.y * 192 + wv * 48;

  f32x4 acc[3][4];
#pragma unroll
  for(int i=0;i<3;i++)
#pragma unroll
    for(int j=0;j<4;j++) acc[i][j] = (f32x4){0.f,0.f,0.f,0.f};

  const int cl = tid >> 3;        // 0..31 : c within k-slice
  const int nn = (tid & 7) * 8;   // 0..56 : n base

  for(int kc=0;kc<6;kc++){
    const int c0 = kc*32;
    __syncthreads();
    const float* xp = x + (size_t)(c0+cl)*NPIX + nb + nn;
    f32x4 v0 = *(const f32x4*)xp;
    f32x4 v1 = *(const f32x4*)(xp+4);
#pragma unroll
    for(int j=0;j<4;j++) Bs[(nn+j)*40 + cl]   = f2bf(v0[j]);
#pragma unroll
    for(int j=0;j<4;j++) Bs[(nn+4+j)*40 + cl] = f2bf(v1[j]);
    __syncthreads();

    bf16x8 a[3];
#pragma unroll
    for(int i=0;i<3;i++)
      a[i] = *(const bf16x8*)(wq + (size_t)(ob + i*16 + l16)*192 + c0 + quad*8);
#pragma unroll
    for(int j=0;j<4;j++){
      bf16x8 b = *(const bf16x8*)&Bs[(j*16 + l16)*40 + quad*8];
#pragma unroll
      for(int i=0;i<3;i++)
        acc[i][j] = __builtin_amdgcn_mfma_f32_16x16x32_bf16(a[i], b, acc[i][j], 0,0,0);
    }
  }
#pragma unroll
  for(int i=0;i<3;i++)
#pragma unroll
    for(int j=0;j<4;j++){
      const int o = ob + i*16 + quad*4;           // C/D: row=(lane>>4)*4+reg, col=lane&15
      const int n = nb + j*16 + l16;
      unsigned short* op = out + (size_t)o*NPIX + n;
#pragma unroll
      for(int r=0;r<4;r++) op[(size_t)r*NPIX] = f2bf(acc[i][j][r]);
    }
}

// shared 4-px dw-conv body; returns sum of squares of the 4 fp32 outputs
__device__ __forceinline__ float dw4(
    const unsigned short* __restrict__ in, const float* __restrict__ wp,
    int n0, unsigned short* __restrict__ dstp)
{
  const int y  = n0 >> 8;
  const int x0 = n0 & 255;
  const float w00=wp[0],w01=wp[1],w02=wp[2],w10=wp[3],w11=wp[4],w12=wp[5],w20=wp[6],w21=wp[7],w22=wp[8];
  const unsigned short* r0 = in + (y-1)*WROW;
  const unsigned short* r1 = in + y*WROW;
  const unsigned short* r2 = in + (y+1)*WROW;
  const bool ht = (y>0), hb = (y<255);
  float t0,m0,b0,t1,m1,b1;
  if(x0>0){ t0 = ht? bf2f(r0[x0-1]):0.f; m0 = bf2f(r1[x0-1]); b0 = hb? bf2f(r2[x0-1]):0.f; }
  else    { t0=m0=b0=0.f; }
  t1 = ht? bf2f(r0[x0]):0.f; m1 = bf2f(r1[x0]); b1 = hb? bf2f(r2[x0]):0.f;
  u16x4 ov; float ss = 0.f;
#pragma unroll
  for(int j=0;j<4;j++){
    const int xx = x0+j;
    float t2,m2,b2;
    if(xx<255){ t2 = ht? bf2f(r0[xx+1]):0.f; m2 = bf2f(r1[xx+1]); b2 = hb? bf2f(r2[xx+1]):0.f; }
    else      { t2=m2=b2=0.f; }
    const float s = t0*w00+t1*w01+t2*w02 + m0*w10+m1*w11+m2*w12 + b0*w20+b1*w21+b2*w22;
    ss += s*s;
    ov[j] = f2bf(s);
    t0=t1;t1=t2;m0=m1;m1=m2;b0=b1;b1=b2;
  }
  *(u16x4*)dstp = ov;
  return ss;
}

// ---------------- K2a: depthwise 3x3 on v channels ----------------
__global__ __launch_bounds__(256) void k_dwconv_v(
    const unsigned short* __restrict__ src, // [192][NPIX] = channels 384..575
    const float* __restrict__ wdw,          // [576][9]
    unsigned short* __restrict__ v)         // [192][NPIX]
{
  const int c  = blockIdx.y;
  const int n0 = blockIdx.x*1024 + threadIdx.x*4;
  dw4(src + (size_t)c*NPIX, wdw + (size_t)(384+c)*9, n0, v + (size_t)c*NPIX + n0);
}

// ---------------- K2: depthwise 3x3 on one head-group of q,k + norms ----------------
// grid (64, 192): block = (1024-px chunk, local channel cc); cc<96: q, else k
__global__ __launch_bounds__(256) void k_dwconv_qk(
    const unsigned short* __restrict__ src, // bufA [384][NPIX]
    const float* __restrict__ wdw,
    unsigned short* __restrict__ dst,       // vbuf [192][NPIX]
    float* __restrict__ qqg, float* __restrict__ kkg,
    int hg)
{
  const int cc  = blockIdx.y;               // 0..191
  const bool isq = (cc < 96);
  const int gch = hg*96 + cc + (isq ? 0 : 96);   // row in bufA == wdw row
  const int n0  = blockIdx.x*1024 + threadIdx.x*4;
  float ss = dw4(src + (size_t)gch*NPIX, wdw + (size_t)gch*9, n0,
                 dst + (size_t)cc*NPIX + n0);
  // wave-level reduce of sum-of-squares, one atomic per wave
#pragma unroll
  for(int off=32; off>=1; off>>=1) ss += __shfl_down(ss, off, 64);
  if((threadIdx.x & 63) == 0){
    float* np = isq ? &qqg[hg*96 + cc] : &kkg[hg*96 + cc - 96];
    atomicAdd(np, ss);
  }
}

// ---------------- K3: Gram G_h[d][e] += sum_n q[d][n] k[e][n] ----------------
// grid (64, 3): block = (1024-px chunk, local head). vbuf rows 0..95 = q, 96..191 = k.
__global__ __launch_bounds__(256) void k_gram(
    const unsigned short* __restrict__ qc,  // vbuf
    float* __restrict__ gram, int hg)
{
  __shared__ __align__(16) unsigned short Qs[32*264];
  __shared__ __align__(16) unsigned short Ks[32*264];
  const int tid  = threadIdx.x;
  const int h    = blockIdx.y;             // 0..2 local head
  const int nb   = blockIdx.x * 1024;
  const int lane = tid & 63;
  const int wv   = tid >> 6;
  const int quad = lane >> 4;
  const int l16  = lane & 15;
  const int d0   = (wv & 1) * 16;
  const int e0   = (wv >> 1) * 16;
  const unsigned short* qp = qc + (size_t)(h*32)*NPIX;
  const unsigned short* kp = qc + (size_t)(96 + h*32)*NPIX;
  f32x4 acc = (f32x4){0.f,0.f,0.f,0.f};

  for(int chk=0; chk<4; chk++){
    const int n1 = nb + chk*256;
    __syncthreads();
#pragma unroll
    for(int r=0;r<4;r++){
      const int base = r*2048 + tid*8;
      const int c  = base >> 8;
      const int xo = base & 255;
      *(bf16x8*)&Qs[c*264 + xo] = *(const bf16x8*)(qp + (size_t)c*NPIX + n1 + xo);
      *(bf16x8*)&Ks[c*264 + xo] = *(const bf16x8*)(kp + (size_t)c*NPIX + n1 + xo);
    }
    __syncthreads();
#pragma unroll
    for(int n=0;n<256;n+=32){
      bf16x8 a = *(const bf16x8*)&Qs[(d0+l16)*264 + n + quad*8];
      bf16x8 b = *(const bf16x8*)&Ks[(e0+l16)*264 + n + quad*8];
      acc = __builtin_amdgcn_mfma_f32_16x16x32_bf16(a, b, acc, 0,0,0);
    }
  }
  float* gp = gram + (size_t)(hg*3 + h)*1024;
#pragma unroll
  for(int r=0;r<4;r++)
    atomicAdd(&gp[(d0 + quad*4 + r)*32 + e0 + l16], acc[r]);
}

// ---------------- K4: attn softmax + Weff = Wproj x blockdiag(attn) ----------------
__global__ __launch_bounds__(256) void k_attn_weff(
    const float* __restrict__ gram, const float* __restrict__ qqg,
    const float* __restrict__ kkg,  const float* __restrict__ temp,
    const float* __restrict__ wproj, unsigned short* __restrict__ weff)
{
  __shared__ float attn[192*32];
  __shared__ float rkk[192];
  const int tid = threadIdx.x;
  if(tid < 192) rkk[tid] = 1.0f / fmaxf(sqrtf(kkg[tid]), 1e-12f);
  __syncthreads();
  if(tid < 192){
    const int h = tid >> 5, d = tid & 31;
    const float rq = 1.0f / fmaxf(sqrtf(qqg[tid]), 1e-12f);
    const float tp = fminf(temp[h], 5.0f);
    float l[32];
    float mx = -1e30f;
#pragma unroll
    for(int e=0;e<32;e++){
      l[e] = gram[(size_t)h*1024 + d*32 + e] * rq * rkk[h*32+e] * tp;
      mx = fmaxf(mx, l[e]);
    }
    float s = 0.f;
#pragma unroll
    for(int e=0;e<32;e++){ l[e] = __expf(l[e]-mx); s += l[e]; }
    const float inv = 1.0f/s;
#pragma unroll
    for(int e=0;e<32;e++) attn[tid*32+e] = l[e]*inv;
  }
  __syncthreads();
  for(int idx = tid; idx < 24*192; idx += 256){
    const int o  = blockIdx.x*24 + idx/192;
    const int cc = idx - (idx/192)*192;
    const int h2 = cc >> 5, e = cc & 31;
    const float* wpp = wproj + (size_t)o*192 + h2*32;
    float s = 0.f;
#pragma unroll
    for(int d=0; d<32; d++) s += wpp[d]*attn[(h2*32+d)*32 + e];
    weff[(size_t)o*192 + cc] = f2bf(s);
  }
}

// ---------------- K5: y = Weff(192x192) @ v(192xN), fp32 out ----------------
__global__ __launch_bounds__(256) void k_proj_gemm(
    const unsigned short* __restrict__ v,    // [192][NPIX] bf16
    const unsigned short* __restrict__ weff, // [192][192] bf16
    float* __restrict__ out)                 // [192][NPIX] fp32
{
  __shared__ __align__(16) unsigned short Bs[64*40];
  const int tid  = threadIdx.x;
  const int lane = tid & 63;
  const int wv   = tid >> 6;
  const int quad = lane >> 4;
  const int l16  = lane & 15;
  const int nb   = blockIdx.x * 64;
  const int ob   = wv * 48;
  f32x4 acc[3][4];
#pragma unroll
  for(int i=0;i<3;i++)
#pragma unroll
    for(int j=0;j<4;j++) acc[i][j] = (f32x4){0.f,0.f,0.f,0.f};
  const int cl = tid >> 3;
  const int nn = (tid & 7)*8;

  for(int kc=0;kc<6;kc++){
    const int c0 = kc*32;
    __syncthreads();
    bf16x8 vv = *(const bf16x8*)(v + (size_t)(c0+cl)*NPIX + nb + nn);
#pragma unroll
    for(int j=0;j<8;j++) Bs[(nn+j)*40 + cl] = (unsigned short)vv[j];
    __syncthreads();
    bf16x8 a[3];
#pragma unroll
    for(int i=0;i<3;i++)
      a[i] = *(const bf16x8*)(weff + (size_t)(ob+i*16+l16)*192 + c0 + quad*8);
#pragma unroll
    for(int j=0;j<4;j++){
      bf16x8 b = *(const bf16x8*)&Bs[(j*16+l16)*40 + quad*8];
#pragma unroll
      for(int i=0;i<3;i++)
        acc[i][j] = __builtin_amdgcn_mfma_f32_16x16x32_bf16(a[i], b, acc[i][j], 0,0,0);
    }
  }
#pragma unroll
  for(int i=0;i<3;i++)
#pragma unroll
    for(int j=0;j<4;j++){
      const int o = ob + i*16 + quad*4;
      const int n = nb + j*16 + l16;
      float* op = out + (size_t)o*NPIX + n;
#pragma unroll
      for(int r=0;r<4;r++) op[(size_t)r*NPIX] = acc[i][j][r];
    }
}

extern "C" void kernel_launch(void* const* d_in, const int* in_sizes, int n_in,
                              void* d_out, int out_size, void* d_ws, size_t ws_size,
                              hipStream_t stream)
{
  (void)in_sizes; (void)n_in; (void)out_size; (void)ws_size;
  const float* x     = (const float*)d_in[0];
  const float* wqkv  = (const float*)d_in[1];
  const float* wdw   = (const float*)d_in[2];
  const float* wproj = (const float*)d_in[3];
  const float* temp  = (const float*)d_in[4];
  float* out = (float*)d_out;

  char* ws = (char*)d_ws;
  unsigned short* bufA = (unsigned short*)(ws);              // 50,331,648 B
  unsigned short* vbuf = (unsigned short*)(ws + 50331648);   // 25,165,824 B
  float*          gram = (float*)(ws + 75497472);            // 6528 floats
  unsigned short* weff = (unsigned short*)(ws + 75523584);   // 73,728 B
  unsigned short* wqbf = (unsigned short*)(ws + 75597312);   // 221,184 B
  float* qqg = gram + 6*1024;
  float* kkg = qqg + 192;

  k_cvt_w<<<dim3(432), dim3(256), 0, stream>>>(wqkv, wqbf, 576*192);

  for(int b=0;b<2;b++){
    const float* xb = x + (size_t)b*192*NPIX;
    float* outb = out + (size_t)b*192*NPIX;
    k_zero<<<dim3(26), dim3(256), 0, stream>>>(gram, 6528);
    // q,k channels (0..383) -> bufA
    k_qkv_gemm<<<dim3(1024,2), dim3(256), 0, stream>>>(xb, wqbf, bufA);
    for(int hg=0; hg<2; hg++){
      k_dwconv_qk<<<dim3(64,192), dim3(256), 0, stream>>>(bufA, wdw, vbuf, qqg, kkg, hg);
      k_gram<<<dim3(64,3), dim3(256), 0, stream>>>(vbuf, gram, hg);
    }
    // v channels (384..575) -> bufA rows 0..191 (reuse)
    k_qkv_gemm<<<dim3(1024,1), dim3(256), 0, stream>>>(xb, wqbf + (size_t)384*192, bufA);
    k_dwconv_v<<<dim3(64,192), dim3(256), 0, stream>>>(bufA, wdw, vbuf);
    k_attn_weff<<<dim3(8), dim3(256), 0, stream>>>(gram, qqg, kkg, temp, wproj, weff);
    k_proj_gemm<<<dim3(1024), dim3(256), 0, stream>>>(vbuf, weff, outb);
  }
}

// Round 3
// 561.298 us; speedup vs baseline: 2.6886x; 2.2956x over previous
//
#include <hip/hip_runtime.h>
#include <stdint.h>

// TransposedAttention (XCA) on MI355X.
// Pipeline per batch:
//   K1  qkv(qk rows) = Wqkv @ x            [bf16 MFMA GEMM, out bf16] -> bufA
//   per head-group hg in {0,1} (3 heads each):
//     K2 dwconv3x3 on 96 q + 96 k channels -> vbuf (bf16), + ||.||^2 block partials
//     K3 Gram q.k^T per head               [MFMA, LDS-staged, atomicAdd]
//   K1b qkv(v rows) -> bufA ; K2a dwconv v -> vbuf
//   K4  reduce norm partials; attn = softmax(norm'd Gram * temp); Weff = Wproj x blockdiag(attn)
//   K5  y = Weff(192x192) @ v(192x65536)   [bf16 MFMA GEMM, out fp32]
// R3 change: k_dwconv_qk's per-wave global atomicAdd to 1.5KB of norm
// accumulators (49K cross-XCD RMWs -> ~200us serialization, the R2 bottleneck)
// replaced with per-block non-atomic partial writes, reduced in k_attn_weff.
//
// ws layout (bytes), peak 75,916,800:
//   0         bufA   [384][65536] bf16
//   50331648  vbuf   [192][65536] bf16
//   75497472  gram   [6][32][32] fp32
//   75523584  weff   [192][192] bf16
//   75597312  wqbf   [576][192] bf16
//   75818496  qqp    [192][64] fp32 partials
//   75867648  kkp    [192][64] fp32 partials

#define NPIX 65536
#define WROW 256

typedef __attribute__((ext_vector_type(4))) float f32x4;
typedef __attribute__((ext_vector_type(8))) short bf16x8;
typedef __attribute__((ext_vector_type(4))) unsigned short u16x4;

__device__ __forceinline__ float bf2f(unsigned short h){
  unsigned int u = ((unsigned int)h) << 16; float f; __builtin_memcpy(&f,&u,4); return f;
}
__device__ __forceinline__ unsigned short f2bf(float f){
  unsigned int u; __builtin_memcpy(&u,&f,4);
  u = (u + 0x7FFFu + ((u>>16)&1u)) >> 16;   // RNE
  return (unsigned short)u;
}

__global__ void k_zero(float* __restrict__ p, int n){
  int i = blockIdx.x*256 + threadIdx.x;
  if(i < n) p[i] = 0.f;
}

__global__ void k_cvt_w(const float* __restrict__ w, unsigned short* __restrict__ o, int n){
  int i = blockIdx.x*256 + threadIdx.x;
  if(i < n) o[i] = f2bf(w[i]);
}

// ---------------- K1: pointwise GEMM  out[row][n] = sum_c wq[row][c]*x[c][n] ----------------
__global__ __launch_bounds__(256) void k_qkv_gemm(
    const float* __restrict__ x,            // [192][NPIX] fp32
    const unsigned short* __restrict__ wq,  // [rows][192] bf16 (pre-offset)
    unsigned short* __restrict__ out)       // [rows][NPIX] bf16
{
  __shared__ __align__(16) unsigned short Bs[64*40];  // [n][c], stride 40
  const int tid  = threadIdx.x;
  const int lane = tid & 63;
  const int wv   = tid >> 6;
  const int quad = lane >> 4;
  const int l16  = lane & 15;
  const int nb   = blockIdx.x * 64;
  const int ob   = blockIdx.y * 192 + wv * 48;

  f32x4 acc[3][4];
#pragma unroll
  for(int i=0;i<3;i++)
#pragma unroll
    for(int j=0;j<4;j++) acc[i][j] = (f32x4){0.f,0.f,0.f,0.f};

  const int cl = tid >> 3;        // 0..31 : c within k-slice
  const int nn = (tid & 7) * 8;   // 0..56 : n base

  for(int kc=0;kc<6;kc++){
    const int c0 = kc*32;
    __syncthreads();
    const float* xp = x + (size_t)(c0+cl)*NPIX + nb + nn;
    f32x4 v0 = *(const f32x4*)xp;
    f32x4 v1 = *(const f32x4*)(xp+4);
#pragma unroll
    for(int j=0;j<4;j++) Bs[(nn+j)*40 + cl]   = f2bf(v0[j]);
#pragma unroll
    for(int j=0;j<4;j++) Bs[(nn+4+j)*40 + cl] = f2bf(v1[j]);
    __syncthreads();

    bf16x8 a[3];
#pragma unroll
    for(int i=0;i<3;i++)
      a[i] = *(const bf16x8*)(wq + (size_t)(ob + i*16 + l16)*192 + c0 + quad*8);
#pragma unroll
    for(int j=0;j<4;j++){
      bf16x8 b = *(const bf16x8*)&Bs[(j*16 + l16)*40 + quad*8];
#pragma unroll
      for(int i=0;i<3;i++)
        acc[i][j] = __builtin_amdgcn_mfma_f32_16x16x32_bf16(a[i], b, acc[i][j], 0,0,0);
    }
  }
#pragma unroll
  for(int i=0;i<3;i++)
#pragma unroll
    for(int j=0;j<4;j++){
      const int o = ob + i*16 + quad*4;           // C/D: row=(lane>>4)*4+reg, col=lane&15
      const int n = nb + j*16 + l16;
      unsigned short* op = out + (size_t)o*NPIX + n;
#pragma unroll
      for(int r=0;r<4;r++) op[(size_t)r*NPIX] = f2bf(acc[i][j][r]);
    }
}

// shared 4-px dw-conv body; returns sum of squares of the 4 fp32 outputs
__device__ __forceinline__ float dw4(
    const unsigned short* __restrict__ in, const float* __restrict__ wp,
    int n0, unsigned short* __restrict__ dstp)
{
  const int y  = n0 >> 8;
  const int x0 = n0 & 255;
  const float w00=wp[0],w01=wp[1],w02=wp[2],w10=wp[3],w11=wp[4],w12=wp[5],w20=wp[6],w21=wp[7],w22=wp[8];
  const unsigned short* r0 = in + (y-1)*WROW;
  const unsigned short* r1 = in + y*WROW;
  const unsigned short* r2 = in + (y+1)*WROW;
  const bool ht = (y>0), hb = (y<255);
  float t0,m0,b0,t1,m1,b1;
  if(x0>0){ t0 = ht? bf2f(r0[x0-1]):0.f; m0 = bf2f(r1[x0-1]); b0 = hb? bf2f(r2[x0-1]):0.f; }
  else    { t0=m0=b0=0.f; }
  t1 = ht? bf2f(r0[x0]):0.f; m1 = bf2f(r1[x0]); b1 = hb? bf2f(r2[x0]):0.f;
  u16x4 ov; float ss = 0.f;
#pragma unroll
  for(int j=0;j<4;j++){
    const int xx = x0+j;
    float t2,m2,b2;
    if(xx<255){ t2 = ht? bf2f(r0[xx+1]):0.f; m2 = bf2f(r1[xx+1]); b2 = hb? bf2f(r2[xx+1]):0.f; }
    else      { t2=m2=b2=0.f; }
    const float s = t0*w00+t1*w01+t2*w02 + m0*w10+m1*w11+m2*w12 + b0*w20+b1*w21+b2*w22;
    ss += s*s;
    ov[j] = f2bf(s);
    t0=t1;t1=t2;m0=m1;m1=m2;b0=b1;b1=b2;
  }
  *(u16x4*)dstp = ov;
  return ss;
}

// ---------------- K2a: depthwise 3x3 on v channels ----------------
__global__ __launch_bounds__(256) void k_dwconv_v(
    const unsigned short* __restrict__ src, // [192][NPIX] = channels 384..575
    const float* __restrict__ wdw,          // [576][9]
    unsigned short* __restrict__ v)         // [192][NPIX]
{
  const int c  = blockIdx.y;
  const int n0 = blockIdx.x*1024 + threadIdx.x*4;
  dw4(src + (size_t)c*NPIX, wdw + (size_t)(384+c)*9, n0, v + (size_t)c*NPIX + n0);
}

// ---------------- K2: depthwise 3x3 on one head-group of q,k + norm partials ----------------
// grid (64, 192): block = (1024-px chunk, local channel cc); cc<96: q, else k
// Norm sum-of-squares: wave shuffle-reduce -> LDS -> ONE non-atomic partial
// store per block into its own [channel][chunk] slot (no contention).
__global__ __launch_bounds__(256) void k_dwconv_qk(
    const unsigned short* __restrict__ src, // bufA [384][NPIX]
    const float* __restrict__ wdw,
    unsigned short* __restrict__ dst,       // vbuf [192][NPIX]
    float* __restrict__ qqp, float* __restrict__ kkp,  // [192][64] partials
    int hg)
{
  __shared__ float wsum[4];
  const int cc  = blockIdx.y;               // 0..191
  const bool isq = (cc < 96);
  const int gch = hg*96 + cc + (isq ? 0 : 96);   // row in bufA == wdw row
  const int n0  = blockIdx.x*1024 + threadIdx.x*4;
  float ss = dw4(src + (size_t)gch*NPIX, wdw + (size_t)gch*9, n0,
                 dst + (size_t)cc*NPIX + n0);
#pragma unroll
  for(int off=32; off>=1; off>>=1) ss += __shfl_down(ss, off, 64);
  const int lane = threadIdx.x & 63;
  const int wv   = threadIdx.x >> 6;
  if(lane == 0) wsum[wv] = ss;
  __syncthreads();
  if(threadIdx.x == 0){
    const float t = wsum[0] + wsum[1] + wsum[2] + wsum[3];
    const int gcc = hg*96 + (isq ? cc : cc - 96);  // global channel within q or k set
    float* pp = isq ? qqp : kkp;
    pp[(size_t)gcc*64 + blockIdx.x] = t;
  }
}

// ---------------- K3: Gram G_h[d][e] += sum_n q[d][n] k[e][n] ----------------
// grid (64, 3): block = (1024-px chunk, local head). vbuf rows 0..95 = q, 96..191 = k.
__global__ __launch_bounds__(256) void k_gram(
    const unsigned short* __restrict__ qc,  // vbuf
    float* __restrict__ gram, int hg)
{
  __shared__ __align__(16) unsigned short Qs[32*264];
  __shared__ __align__(16) unsigned short Ks[32*264];
  const int tid  = threadIdx.x;
  const int h    = blockIdx.y;             // 0..2 local head
  const int nb   = blockIdx.x * 1024;
  const int lane = tid & 63;
  const int wv   = tid >> 6;
  const int quad = lane >> 4;
  const int l16  = lane & 15;
  const int d0   = (wv & 1) * 16;
  const int e0   = (wv >> 1) * 16;
  const unsigned short* qp = qc + (size_t)(h*32)*NPIX;
  const unsigned short* kp = qc + (size_t)(96 + h*32)*NPIX;
  f32x4 acc = (f32x4){0.f,0.f,0.f,0.f};

  for(int chk=0; chk<4; chk++){
    const int n1 = nb + chk*256;
    __syncthreads();
#pragma unroll
    for(int r=0;r<4;r++){
      const int base = r*2048 + tid*8;
      const int c  = base >> 8;
      const int xo = base & 255;
      *(bf16x8*)&Qs[c*264 + xo] = *(const bf16x8*)(qp + (size_t)c*NPIX + n1 + xo);
      *(bf16x8*)&Ks[c*264 + xo] = *(const bf16x8*)(kp + (size_t)c*NPIX + n1 + xo);
    }
    __syncthreads();
#pragma unroll
    for(int n=0;n<256;n+=32){
      bf16x8 a = *(const bf16x8*)&Qs[(d0+l16)*264 + n + quad*8];
      bf16x8 b = *(const bf16x8*)&Ks[(e0+l16)*264 + n + quad*8];
      acc = __builtin_amdgcn_mfma_f32_16x16x32_bf16(a, b, acc, 0,0,0);
    }
  }
  float* gp = gram + (size_t)(hg*3 + h)*1024;
#pragma unroll
  for(int r=0;r<4;r++)
    atomicAdd(&gp[(d0 + quad*4 + r)*32 + e0 + l16], acc[r]);
}

// ---------------- K4: partial-reduce norms; attn softmax; Weff = Wproj x blockdiag(attn) ----------------
__global__ __launch_bounds__(256) void k_attn_weff(
    const float* __restrict__ gram,
    const float* __restrict__ qqp, const float* __restrict__ kkp,  // [192][64]
    const float* __restrict__ temp,
    const float* __restrict__ wproj, unsigned short* __restrict__ weff)
{
  __shared__ float attn[192*32];
  __shared__ float rkk[192];
  const int tid = threadIdx.x;
  float qq = 0.f;
  if(tid < 192){
    const f32x4* kp4 = (const f32x4*)(kkp + (size_t)tid*64);
    const f32x4* qp4 = (const f32x4*)(qqp + (size_t)tid*64);
    f32x4 ks = (f32x4){0.f,0.f,0.f,0.f};
    f32x4 qs = (f32x4){0.f,0.f,0.f,0.f};
#pragma unroll
    for(int i=0;i<16;i++){ ks += kp4[i]; qs += qp4[i]; }
    const float kk = ks[0]+ks[1]+ks[2]+ks[3];
    qq = qs[0]+qs[1]+qs[2]+qs[3];
    rkk[tid] = 1.0f / fmaxf(sqrtf(kk), 1e-12f);
  }
  __syncthreads();
  if(tid < 192){
    const int h = tid >> 5, d = tid & 31;
    const float rq = 1.0f / fmaxf(sqrtf(qq), 1e-12f);
    const float tp = fminf(temp[h], 5.0f);
    float l[32];
    float mx = -1e30f;
#pragma unroll
    for(int e=0;e<32;e++){
      l[e] = gram[(size_t)h*1024 + d*32 + e] * rq * rkk[h*32+e] * tp;
      mx = fmaxf(mx, l[e]);
    }
    float s = 0.f;
#pragma unroll
    for(int e=0;e<32;e++){ l[e] = __expf(l[e]-mx); s += l[e]; }
    const float inv = 1.0f/s;
#pragma unroll
    for(int e=0;e<32;e++) attn[tid*32+e] = l[e]*inv;
  }
  __syncthreads();
  for(int idx = tid; idx < 24*192; idx += 256){
    const int o  = blockIdx.x*24 + idx/192;
    const int cc = idx - (idx/192)*192;
    const int h2 = cc >> 5, e = cc & 31;
    const float* wpp = wproj + (size_t)o*192 + h2*32;
    float s = 0.f;
#pragma unroll
    for(int d=0; d<32; d++) s += wpp[d]*attn[(h2*32+d)*32 + e];
    weff[(size_t)o*192 + cc] = f2bf(s);
  }
}

// ---------------- K5: y = Weff(192x192) @ v(192xN), fp32 out ----------------
__global__ __launch_bounds__(256) void k_proj_gemm(
    const unsigned short* __restrict__ v,    // [192][NPIX] bf16
    const unsigned short* __restrict__ weff, // [192][192] bf16
    float* __restrict__ out)                 // [192][NPIX] fp32
{
  __shared__ __align__(16) unsigned short Bs[64*40];
  const int tid  = threadIdx.x;
  const int lane = tid & 63;
  const int wv   = tid >> 6;
  const int quad = lane >> 4;
  const int l16  = lane & 15;
  const int nb   = blockIdx.x * 64;
  const int ob   = wv * 48;
  f32x4 acc[3][4];
#pragma unroll
  for(int i=0;i<3;i++)
#pragma unroll
    for(int j=0;j<4;j++) acc[i][j] = (f32x4){0.f,0.f,0.f,0.f};
  const int cl = tid >> 3;
  const int nn = (tid & 7)*8;

  for(int kc=0;kc<6;kc++){
    const int c0 = kc*32;
    __syncthreads();
    bf16x8 vv = *(const bf16x8*)(v + (size_t)(c0+cl)*NPIX + nb + nn);
#pragma unroll
    for(int j=0;j<8;j++) Bs[(nn+j)*40 + cl] = (unsigned short)vv[j];
    __syncthreads();
    bf16x8 a[3];
#pragma unroll
    for(int i=0;i<3;i++)
      a[i] = *(const bf16x8*)(weff + (size_t)(ob+i*16+l16)*192 + c0 + quad*8);
#pragma unroll
    for(int j=0;j<4;j++){
      bf16x8 b = *(const bf16x8*)&Bs[(j*16+l16)*40 + quad*8];
#pragma unroll
      for(int i=0;i<3;i++)
        acc[i][j] = __builtin_amdgcn_mfma_f32_16x16x32_bf16(a[i], b, acc[i][j], 0,0,0);
    }
  }
#pragma unroll
  for(int i=0;i<3;i++)
#pragma unroll
    for(int j=0;j<4;j++){
      const int o = ob + i*16 + quad*4;
      const int n = nb + j*16 + l16;
      float* op = out + (size_t)o*NPIX + n;
#pragma unroll
      for(int r=0;r<4;r++) op[(size_t)r*NPIX] = acc[i][j][r];
    }
}

extern "C" void kernel_launch(void* const* d_in, const int* in_sizes, int n_in,
                              void* d_out, int out_size, void* d_ws, size_t ws_size,
                              hipStream_t stream)
{
  (void)in_sizes; (void)n_in; (void)out_size; (void)ws_size;
  const float* x     = (const float*)d_in[0];
  const float* wqkv  = (const float*)d_in[1];
  const float* wdw   = (const float*)d_in[2];
  const float* wproj = (const float*)d_in[3];
  const float* temp  = (const float*)d_in[4];
  float* out = (float*)d_out;

  char* ws = (char*)d_ws;
  unsigned short* bufA = (unsigned short*)(ws);              // 50,331,648 B
  unsigned short* vbuf = (unsigned short*)(ws + 50331648);   // 25,165,824 B
  float*          gram = (float*)(ws + 75497472);            // 6144 floats
  unsigned short* weff = (unsigned short*)(ws + 75523584);   // 73,728 B
  unsigned short* wqbf = (unsigned short*)(ws + 75597312);   // 221,184 B
  float*          qqp  = (float*)(ws + 75818496);            // [192][64]
  float*          kkp  = (float*)(ws + 75867648);            // [192][64]

  k_cvt_w<<<dim3(432), dim3(256), 0, stream>>>(wqkv, wqbf, 576*192);

  for(int b=0;b<2;b++){
    const float* xb = x + (size_t)b*192*NPIX;
    float* outb = out + (size_t)b*192*NPIX;
    k_zero<<<dim3(24), dim3(256), 0, stream>>>(gram, 6144);
    // q,k channels (0..383) -> bufA
    k_qkv_gemm<<<dim3(1024,2), dim3(256), 0, stream>>>(xb, wqbf, bufA);
    for(int hg=0; hg<2; hg++){
      k_dwconv_qk<<<dim3(64,192), dim3(256), 0, stream>>>(bufA, wdw, vbuf, qqp, kkp, hg);
      k_gram<<<dim3(64,3), dim3(256), 0, stream>>>(vbuf, gram, hg);
    }
    // v channels (384..575) -> bufA rows 0..191 (reuse)
    k_qkv_gemm<<<dim3(1024,1), dim3(256), 0, stream>>>(xb, wqbf + (size_t)384*192, bufA);
    k_dwconv_v<<<dim3(64,192), dim3(256), 0, stream>>>(bufA, wdw, vbuf);
    k_attn_weff<<<dim3(8), dim3(256), 0, stream>>>(gram, qqp, kkp, temp, wproj, weff);
    k_proj_gemm<<<dim3(1024), dim3(256), 0, stream>>>(vbuf, weff, outb);
  }
}